// Round 1
// baseline (249.518 us; speedup 1.0000x reference)
//
#include <hip/hip_runtime.h>
#include <hip/hip_bf16.h>
#include <math.h>

#define DIM 64
#define KN 16
#define NREL 32

__device__ __forceinline__ float lane_bcast(float v, int l) {
    return __int_as_float(__builtin_amdgcn_readlane(__float_as_int(v), l));
}

__global__ __launch_bounds__(256) void kgcn_kernel(
    const int* __restrict__ pairs,
    const int* __restrict__ adj_entity,
    const int* __restrict__ adj_relation,
    const float* __restrict__ entity_emb,
    const float* __restrict__ relation_emb,
    const float* __restrict__ user_emb,
    const float* __restrict__ W,
    const float* __restrict__ bias,
    float* __restrict__ out)
{
    __shared__ float REL[NREL * DIM];   // 8 KB: relation embeddings
    __shared__ float su[DIM];           // user embedding
    __shared__ float sb[DIM];           // bias
    __shared__ float ur[NREL];          // dot(u, relation_emb[r]) for all r
    __shared__ float ev1[KN * DIM];     // layer-0 outputs for the 16 hop-1 groups
    __shared__ int   se1[KN];           // hop-1 entity ids

    const int bi   = blockIdx.x;
    const int tid  = threadIdx.x;
    const int wave = tid >> 6;
    const int lane = tid & 63;

    const int user = pairs[2 * bi + 0];
    const int item = pairs[2 * bi + 1];

    // ---- stage constants ----
    for (int i = tid; i < NREL * DIM; i += 256) REL[i] = relation_emb[i];
    if (tid < DIM) su[tid] = user_emb[user * DIM + tid];
    if (tid < DIM) sb[tid] = bias[tid];
    if (tid < KN)  se1[tid] = adj_entity[item * KN + tid];
    __syncthreads();

    // ---- W rows into registers: lane d holds W[d][0..63] ----
    float Wreg[DIM];
    {
        const float4* W4 = (const float4*)W;
        #pragma unroll
        for (int jj = 0; jj < 16; ++jj) {
            float4 w = W4[lane * 16 + jj];
            Wreg[4 * jj + 0] = w.x;
            Wreg[4 * jj + 1] = w.y;
            Wreg[4 * jj + 2] = w.z;
            Wreg[4 * jj + 3] = w.w;
        }
    }

    // ---- ur[r] = dot(u, REL[r]) : 256 threads = 32 relations x 8 chunks ----
    {
        const int r = tid >> 3;   // 0..31
        const int j = tid & 7;    // 0..7
        float p = 0.f;
        #pragma unroll
        for (int d = 0; d < 8; ++d)
            p += su[j * 8 + d] * REL[r * DIM + j * 8 + d];
        p += __shfl_xor(p, 1);
        p += __shfl_xor(p, 2);
        p += __shfl_xor(p, 4);
        if (j == 0) ur[r] = p;
    }
    __syncthreads();

    const float u = su[lane];

    // ---- Layer 0, hop i=1: 16 groups, 4 per wave ----
    for (int mi = 0; mi < 4; ++mi) {
        const int m = wave * 4 + mi;
        const int g = se1[m];

        int rk = 0, ek = 0;
        if (lane < KN) {
            rk = adj_relation[g * KN + lane];
            ek = adj_entity[g * KN + lane];
        }

        // scores from precomputed ur table (redundant per lane, cheap)
        float sc[KN];
        #pragma unroll
        for (int k = 0; k < KN; ++k) {
            const int rkb = __shfl(rk, k);
            sc[k] = ur[rkb];
        }
        float mx = sc[0];
        #pragma unroll
        for (int k = 1; k < KN; ++k) mx = fmaxf(mx, sc[k]);
        float ssum = 0.f;
        #pragma unroll
        for (int k = 0; k < KN; ++k) { sc[k] = expf(sc[k] - mx); ssum += sc[k]; }
        const float inv = 1.f / ssum;

        // x = self + attention-weighted neighbor sum (coalesced 256B gathers)
        float x = entity_emb[g * DIM + lane];
        #pragma unroll
        for (int k = 0; k < KN; ++k) {
            const int ekb = __shfl(ek, k);
            x += (sc[k] * inv) * entity_emb[(long)ekb * DIM + lane];
        }

        // h[lane] = sum_j x_j * W[lane][j] + b[lane], relu
        float h = sb[lane];
        #pragma unroll
        for (int j = 0; j < DIM; ++j)
            h += lane_bcast(x, j) * Wreg[j];
        ev1[m * DIM + lane] = fmaxf(h, 0.f);
    }
    __syncthreads();

    // ---- hop i=0 (layer 0 then layer 1) on wave 0 only ----
    if (wave == 0) {
        int rk = 0, ek = 0;
        if (lane < KN) {
            rk = adj_relation[item * KN + lane];
            ek = se1[lane];
        }
        float sc[KN];
        #pragma unroll
        for (int k = 0; k < KN; ++k) {
            const int rkb = __shfl(rk, k);
            sc[k] = ur[rkb];
        }
        float mx = sc[0];
        #pragma unroll
        for (int k = 1; k < KN; ++k) mx = fmaxf(mx, sc[k]);
        float ssum = 0.f;
        #pragma unroll
        for (int k = 0; k < KN; ++k) { sc[k] = expf(sc[k] - mx); ssum += sc[k]; }
        const float inv = 1.f / ssum;

        // layer 0, i=0: neighbors are the raw e1 entity embeddings
        float x0 = entity_emb[(long)item * DIM + lane];
        #pragma unroll
        for (int k = 0; k < KN; ++k) {
            const int ekb = __shfl(ek, k);
            x0 += (sc[k] * inv) * entity_emb[(long)ekb * DIM + lane];
        }
        float h0 = sb[lane];
        #pragma unroll
        for (int j = 0; j < DIM; ++j)
            h0 += lane_bcast(x0, j) * Wreg[j];
        const float e0 = fmaxf(h0, 0.f);

        // layer 1, i=0: same attention, neighbors are layer-0 outputs ev1
        float x1 = e0;
        #pragma unroll
        for (int k = 0; k < KN; ++k)
            x1 += (sc[k] * inv) * ev1[k * DIM + lane];
        float h1 = sb[lane];
        #pragma unroll
        for (int j = 0; j < DIM; ++j)
            h1 += lane_bcast(x1, j) * Wreg[j];
        const float itemf = tanhf(h1);

        // out = sigmoid(dot(u, item_embedding))
        float p = u * itemf;
        p += __shfl_xor(p, 1);
        p += __shfl_xor(p, 2);
        p += __shfl_xor(p, 4);
        p += __shfl_xor(p, 8);
        p += __shfl_xor(p, 16);
        p += __shfl_xor(p, 32);
        if (lane == 0) out[bi] = 1.f / (1.f + expf(-p));
    }
}

extern "C" void kernel_launch(void* const* d_in, const int* in_sizes, int n_in,
                              void* d_out, int out_size, void* d_ws, size_t ws_size,
                              hipStream_t stream) {
    const int*   pairs        = (const int*)d_in[0];
    const int*   adj_entity   = (const int*)d_in[1];
    const int*   adj_relation = (const int*)d_in[2];
    const float* entity_emb   = (const float*)d_in[3];
    const float* relation_emb = (const float*)d_in[4];
    const float* user_emb     = (const float*)d_in[5];
    const float* W            = (const float*)d_in[6];
    const float* b            = (const float*)d_in[7];
    float* out = (float*)d_out;

    const int nB = in_sizes[0] / 2;   // pairs is (B, 2)
    kgcn_kernel<<<nB, 256, 0, stream>>>(pairs, adj_entity, adj_relation,
                                        entity_emb, relation_emb, user_emb,
                                        W, b, out);
}

// Round 2
// 177.949 us; speedup vs baseline: 1.4022x; 1.4022x over previous
//
#include <hip/hip_runtime.h>
#include <math.h>

#define DIM  64
#define KN   16
#define NREL 32
#define PPB  4   // pairs (= waves) per 256-thread block

__device__ __forceinline__ float frcp(float x) { return __builtin_amdgcn_rcpf(x); }

__global__ __launch_bounds__(256, 4) void kgcn_kernel(
    const int* __restrict__ pairs,
    const int* __restrict__ adj_entity,
    const int* __restrict__ adj_relation,
    const float* __restrict__ entity_emb,
    const float* __restrict__ relation_emb,
    const float* __restrict__ user_emb,
    const float* __restrict__ W,
    const float* __restrict__ bias,
    float* __restrict__ out,
    int nPairs)
{
    // Per-wave private LDS regions: waves never share data -> zero barriers.
    __shared__ float ur_s[PPB][NREL];      // dot(u, rel_r) table
    __shared__ float ev1_s[PPB][KN * DIM]; // layer-0 outputs of the 16 hop-1 groups
    __shared__ float xb_s[PPB][DIM];       // matvec broadcast buffer

    const int tid  = threadIdx.x;
    const int wave = tid >> 6;
    const int lane = tid & 63;
    const int p    = blockIdx.x * PPB + wave;
    if (p >= nPairs) return;   // no barriers anywhere -> safe early-out

    float* ur  = ur_s[wave];
    float* ev1 = ev1_s[wave];
    float* xb  = xb_s[wave];

    const int user = pairs[2 * p + 0];
    const int item = pairs[2 * p + 1];

    const float bval = bias[lane];
    const float uval = user_emb[(size_t)user * DIM + lane];
    const float* emb_l = entity_emb + lane;

    // ---- W rows into registers: lane d holds W[d][0..63] (L1-hot, once/wave) ----
    float Wreg[DIM];
    {
        const float4* W4 = (const float4*)W;
        #pragma unroll
        for (int jj = 0; jj < 16; ++jj) {
            float4 w = W4[lane * 16 + jj];
            Wreg[4*jj+0] = w.x; Wreg[4*jj+1] = w.y;
            Wreg[4*jj+2] = w.z; Wreg[4*jj+3] = w.w;
        }
    }

    // ---- hop-0 adjacency (item row); e1 = the 16 hop-1 group ids ----
    int e1 = 0, rk0 = 0;
    if (lane < KN) {
        e1  = adj_entity[(size_t)item * KN + lane];
        rk0 = adj_relation[(size_t)item * KN + lane];
    }
    const int ek0 = e1;  // hop-0 neighbors ARE the hop-1 group ids

    // ---- ur[r] = dot(u, relation_emb[r]), r in [0,32): 2 lanes per relation ----
    {
        const int r = lane >> 1, half = lane & 1;
        const float4* rel4 = (const float4*)(relation_emb + r * DIM + half * 32);
        const float4* usr4 = (const float4*)(user_emb + (size_t)user * DIM + half * 32);
        float acc = 0.f;
        #pragma unroll
        for (int jj = 0; jj < 8; ++jj) {
            float4 a = rel4[jj], b = usr4[jj];
            acc += a.x*b.x + a.y*b.y + a.z*b.z + a.w*b.w;
        }
        acc += __shfl_xor(acc, 1);
        if (half == 0) ur[r] = acc;
        asm volatile("s_waitcnt lgkmcnt(0)" ::: "memory");
    }

    // softmax over the 16 lanes holding one score each (lanes>=16 harmless)
    auto softmax_w = [&](int rk) -> float {
        float s = ur[rk & (NREL - 1)];
        float mx = s;
        mx = fmaxf(mx, __shfl_xor(mx, 1));
        mx = fmaxf(mx, __shfl_xor(mx, 2));
        mx = fmaxf(mx, __shfl_xor(mx, 4));
        mx = fmaxf(mx, __shfl_xor(mx, 8));
        float e = __expf(s - mx);
        float ss = e;
        ss += __shfl_xor(ss, 1);
        ss += __shfl_xor(ss, 2);
        ss += __shfl_xor(ss, 4);
        ss += __shfl_xor(ss, 8);
        return e * frcp(ss);
    };

    // x = self + sum_k w_k * entity_emb[ek_k]  (coalesced 256B gathers)
    auto gather = [&](int g, int ek, float w) -> float {
        float x = emb_l[(size_t)(unsigned)g * DIM];
        #pragma unroll
        for (int k = 0; k < KN; ++k) {
            const int   ekb = __shfl(ek, k);
            const float wk  = __shfl(w,  k);
            x += wk * emb_l[(size_t)(unsigned)ekb * DIM];
        }
        return x;
    };

    // h[lane] = b[lane] + sum_j x_j * W[lane][j] via LDS-broadcast b128 reads
    auto matvec = [&](float x) -> float {
        asm volatile("s_waitcnt lgkmcnt(0)" ::: "memory");  // WAR vs prior xb reads
        xb[lane] = x;
        asm volatile("s_waitcnt lgkmcnt(0)" ::: "memory");  // write visible to wave
        float h = bval;
        #pragma unroll
        for (int j = 0; j < 16; ++j) {
            float4 xv = ((const float4*)xb)[j];  // same addr all lanes: broadcast
            h += xv.x * Wreg[4*j+0] + xv.y * Wreg[4*j+1]
               + xv.z * Wreg[4*j+2] + xv.w * Wreg[4*j+3];
        }
        return h;
    };

    // hop-0 attention weights early (loads already in flight)
    const float w0 = softmax_w(rk0);

    // ---- layer 0, hop 1: 16 groups, adjacency software-prefetched ----
    int rk_n = 0, ek_n = 0;
    {
        const int g0 = __shfl(e1, 0);
        if (lane < KN) {
            rk_n = adj_relation[(size_t)(unsigned)g0 * KN + lane];
            ek_n = adj_entity[(size_t)(unsigned)g0 * KN + lane];
        }
    }
    #pragma unroll 1
    for (int m = 0; m < KN; ++m) {
        const int g  = __shfl(e1, m);
        const int rk = rk_n;
        const int ek = ek_n;
        if (m + 1 < KN) {
            const int gn = __shfl(e1, m + 1);
            if (lane < KN) {
                rk_n = adj_relation[(size_t)(unsigned)gn * KN + lane];
                ek_n = adj_entity[(size_t)(unsigned)gn * KN + lane];
            }
        }
        const float w = softmax_w(rk);
        const float x = gather(g, ek, w);
        const float h = matvec(x);
        ev1[m * DIM + lane] = fmaxf(h, 0.f);
    }

    // ---- hop 0: layer 0 (entity neighbors), then layer 1 (ev1 neighbors) ----
    const float x0 = gather(item, ek0, w0);
    const float e0 = fmaxf(matvec(x0), 0.f);

    asm volatile("s_waitcnt lgkmcnt(0)" ::: "memory");
    float x1 = e0;
    #pragma unroll
    for (int k = 0; k < KN; ++k) {
        const float wk = __shfl(w0, k);
        x1 += wk * ev1[k * DIM + lane];
    }
    const float itemf = tanhf(matvec(x1));

    // out = sigmoid(dot(u, item_embedding))
    float acc = uval * itemf;
    acc += __shfl_xor(acc, 1);
    acc += __shfl_xor(acc, 2);
    acc += __shfl_xor(acc, 4);
    acc += __shfl_xor(acc, 8);
    acc += __shfl_xor(acc, 16);
    acc += __shfl_xor(acc, 32);
    if (lane == 0) out[p] = 1.f / (1.f + expf(-acc));
}

extern "C" void kernel_launch(void* const* d_in, const int* in_sizes, int n_in,
                              void* d_out, int out_size, void* d_ws, size_t ws_size,
                              hipStream_t stream) {
    const int*   pairs        = (const int*)d_in[0];
    const int*   adj_entity   = (const int*)d_in[1];
    const int*   adj_relation = (const int*)d_in[2];
    const float* entity_emb   = (const float*)d_in[3];
    const float* relation_emb = (const float*)d_in[4];
    const float* user_emb     = (const float*)d_in[5];
    const float* W            = (const float*)d_in[6];
    const float* b            = (const float*)d_in[7];
    float* out = (float*)d_out;

    const int nPairs  = in_sizes[0] / 2;   // pairs is (B, 2)
    const int nBlocks = (nPairs + PPB - 1) / PPB;
    kgcn_kernel<<<nBlocks, 256, 0, stream>>>(pairs, adj_entity, adj_relation,
                                             entity_emb, relation_emb, user_emb,
                                             W, b, out, nPairs);
}